// Round 9
// baseline (527.497 us; speedup 1.0000x reference)
//
#include <hip/hip_runtime.h>

#define BATCH 8
#define PN    16384
#define NSAMP 256
#define KDIM  512
#define HID   384
#define HALF  192
#define CIN   576   // HID + HALF
#define ROWS  2048  // BATCH * NSAMP
#define BN_EPS 1e-5f

// workspace offsets (in floats)
#define OFF_GF   0
#define OFF_W1T  3072      /* local-part transpose: [192][384] = 73728 */
#define OFF_GFW  76800     /* per-batch gf@W1_glob + b1: [8][384] */
#define OFF_W2T  224256
#define OFF_IDX  371712    /* 2048 ints */
#define OFF_H1   373760    /* ALSO: FPS q-array [8][16384] float4, dead before gemm1 writes H1 */
#define OFF_H2   1160192
#define OFF_SUM1 1946624
#define OFF_SQ1  1947008
#define OFF_SUM2 1947392
#define OFF_SQ2  1947776

typedef float v2f __attribute__((ext_vector_type(2)));

// one DPP max step: v = max(v, dpp_move(v)); masked lanes read 0 (identity
// for dist >= 0). Sequence hardware-verified in earlier passing rounds;
// accumulates the wave max into lane 63.
#define DPP_MAX(v, ctrl)                                                   \
  v = fmaxf(v, __int_as_float(__builtin_amdgcn_update_dpp(                 \
          0, __float_as_int(v), (ctrl), 0xf, 0xf, true)))
// unsigned variant, identity 0
#define DPP_UMAX(v, ctrl)                                                  \
  {                                                                        \
    unsigned _o = (unsigned)__builtin_amdgcn_update_dpp(                   \
        0, (int)(v), (ctrl), 0xf, 0xf, true);                              \
    v = (_o > (v)) ? _o : (v);                                             \
  }

// ---- K1: fused FPS (blocks 0..7) + prep (blocks 8..32) --------------------
// FPS on 192-dim local_feat == FPS on 3-dim p under metric G = Wc Wc^T = LL^T.
// q = L^T p; d(i,c) = n_i - 2<q_i,q_c> + n_c, n=|q|^2 in regs.
// SINGLE barrier per step: block argmax resolved pre-barrier via one LDS
// atomicMax per wave on a packed u64 key {dist_bits:32, ~index:32}
// (max key = larger dist, ties -> smaller index = jnp.argmax first-index).
// Per-lane index scan (vs tmax) overlaps the f32 DPP chain; readlane(63)
// broadcasts the true wave max; a u32 DPP chain accumulates ~mi over
// qualified lanes. Triple-buffered key: reset of buf[(k+2)%3] placed
// POST-barrier (after all step-(k-1) readers, before step-(k+2) writers).
__global__ __launch_bounds__(1024)
void k_main(const float* p, const float* Wc,
            const float* pf, const float* Wf,
            const float* bfe, const float* W1,
            const float* b1v, const float* W2,
            float* ws) {
  __shared__ float s[KDIM];
  __shared__ float Msh[6];
  __shared__ unsigned long long gkey[3];
  int blk = blockIdx.x, t = threadIdx.x;

  if (blk >= 8) {                    // ---- prep work, hidden under FPS ----
    if (blk < 16) {                  // W1t_loc[c][o] = W1[o][HID + c], c<192
      for (int sI = (blk - 8) * 1024 + t; sI < HID * HALF; sI += 8192) {
        int o = sI / HALF, c = sI % HALF;
        ws[OFF_W1T + c * HID + o] = W1[o * CIN + HID + c];
      }
    } else if (blk < 24) {           // W2t[c][o] = W2[o][c]
      for (int sI = (blk - 16) * 1024 + t; sI < HID * HID; sI += 8192) {
        int o = sI / HID, c = sI % HID;
        ws[OFF_W2T + c * HID + o] = W2[sI];
      }
    } else if (blk < 32) {           // gf[b] = pf[b]@W_feat + b_feat ; then
      int b = blk - 24;              // gfW[b] = b1 + gf[b]@W1_glob (per-batch)
      if (t < KDIM) s[t] = pf[b * KDIM + t];
      __syncthreads();
      float acc = 0.f;
      if (t < HID) {
        acc = bfe[t];
        for (int k = 0; k < KDIM; k++) acc = fmaf(s[k], Wf[k * HID + t], acc);
        ws[OFF_GF + b * HID + t] = acc;
      }
      __syncthreads();               // all reads of s done
      if (t < HID) s[t] = acc;       // reuse s[0..383] for gf
      __syncthreads();
      if (t < HID) {
        float g = b1v[t];
        const float* w1row = W1 + t * CIN;   // row o=t, glob channels 0..383
        for (int c = 0; c < HID; c++) g = fmaf(s[c], w1row[c], g);
        ws[OFF_GFW + b * HID + t] = g;
      }
    } else {                         // zero BN sums (contiguous 1536 floats)
      for (int i = t; i < 1536; i += 1024) ws[OFF_SUM1 + i] = 0.f;
    }
    return;
  }

  // ---- FPS, one batch per block ----
  int b = blk;
  int* idx_out = (int*)(ws + OFF_IDX);

  if (t < 64) {                      // G (3x3) in fp64 + Cholesky, wave 0
    double g0 = 0, g1 = 0, g2 = 0, g3 = 0, g4 = 0, g5 = 0;
    for (int k = t; k < HALF; k += 64) {
      double w0 = (double)Wc[k];
      double w1 = (double)Wc[HALF + k];
      double w2 = (double)Wc[2 * HALF + k];
      g0 += w0 * w0; g1 += w0 * w1; g2 += w0 * w2;
      g3 += w1 * w1; g4 += w1 * w2; g5 += w2 * w2;
    }
    for (int off = 32; off; off >>= 1) {
      g0 += __shfl_down(g0, off, 64); g1 += __shfl_down(g1, off, 64);
      g2 += __shfl_down(g2, off, 64); g3 += __shfl_down(g3, off, 64);
      g4 += __shfl_down(g4, off, 64); g5 += __shfl_down(g5, off, 64);
    }
    if (t == 0) {
      double l00 = sqrt(g0);
      double l10 = g1 / l00, l20 = g2 / l00;
      double l11 = sqrt(g3 - l10 * l10);
      double l21 = (g4 - l10 * l20) / l11;
      double l22 = sqrt(g5 - l20 * l20 - l21 * l21);
      Msh[0] = (float)l00; Msh[1] = (float)l10; Msh[2] = (float)l20;
      Msh[3] = (float)l11; Msh[4] = (float)l21; Msh[5] = (float)l22;
    }
  }
  __syncthreads();
  float m00 = Msh[0], m10 = Msh[1], m20 = Msh[2];
  float m11 = Msh[3], m21 = Msh[4], m22 = Msh[5];

  const float* pb = p + b * PN * 3;
  float4* qws = (float4*)(ws + OFF_H1) + b * PN;  // staged {q, |q|^2}
  // ownership: pair j holds global points i0=(2j)*1024+t and i1=i0+1024
  v2f qx[8], qy[8], qz[8], nq[8], dist[8];
#pragma unroll
  for (int j = 0; j < 8; j++) {
    int i0 = ((2 * j) << 10) + t;
    int i1 = i0 + 1024;
    float x0 = pb[i0 * 3], y0 = pb[i0 * 3 + 1], z0 = pb[i0 * 3 + 2];
    float x1 = pb[i1 * 3], y1 = pb[i1 * 3 + 1], z1 = pb[i1 * 3 + 2];
    qx[j] = (v2f){fmaf(m00, x0, fmaf(m10, y0, m20 * z0)),
                  fmaf(m00, x1, fmaf(m10, y1, m20 * z1))};
    qy[j] = (v2f){fmaf(m11, y0, m21 * z0), fmaf(m11, y1, m21 * z1)};
    qz[j] = (v2f){m22 * z0, m22 * z1};
    nq[j] = __builtin_elementwise_fma(
        qx[j], qx[j],
        __builtin_elementwise_fma(qy[j], qy[j], qz[j] * qz[j]));
    dist[j] = (v2f){1e10f, 1e10f};
    qws[i0] = make_float4(qx[j].x, qy[j].x, qz[j].x, nq[j].x);
    qws[i1] = make_float4(qx[j].y, qy[j].y, qz[j].y, nq[j].y);
  }

  if (t == 0) { gkey[0] = 0ull; gkey[1] = 0ull; gkey[2] = 0ull; }
  __syncthreads();                   // q-array + seeds visible to block

  int far = 0;                       // step-0 selection (jnp FPS starts at 0)
  for (int k = 0; k < NSAMP; k++) {
    float4 qc = qws[far];            // one uniform b128 load (L2)
    float cx2 = -2.f * qc.x, cy2 = -2.f * qc.y, cz2 = -2.f * qc.z;
    v2f cxv = (v2f){cx2, cx2}, cyv = (v2f){cy2, cy2}, czv = (v2f){cz2, cz2};
    v2f ncv = (v2f){qc.w, qc.w};
#pragma unroll
    for (int j = 0; j < 8; j++) {    // d = n_i - 2<q,c> + n_c, packed
      v2f base = nq[j] + ncv;
      v2f d = __builtin_elementwise_fma(
          qx[j], cxv,
          __builtin_elementwise_fma(qy[j], cyv,
              __builtin_elementwise_fma(qz[j], czv, base)));
      dist[j] = __builtin_elementwise_min(dist[j], d);
    }
    if (t == 0) idx_out[b * NSAMP + k] = far;  // off the critical path
    // per-thread max of 16 (packed tree)
    v2f t0v = __builtin_elementwise_max(dist[0], dist[1]);
    v2f t1v = __builtin_elementwise_max(dist[2], dist[3]);
    v2f t2v = __builtin_elementwise_max(dist[4], dist[5]);
    v2f t3v = __builtin_elementwise_max(dist[6], dist[7]);
    t0v = __builtin_elementwise_max(t0v, t1v);
    t2v = __builtin_elementwise_max(t2v, t3v);
    t0v = __builtin_elementwise_max(t0v, t2v);
    float tmax = fmaxf(t0v.x, t0v.y);
    // per-lane smallest owned index achieving tmax (descending predicated
    // selects; independent of the DPP chain -> overlaps it)
    int mi = 0x7fffffff;
#pragma unroll
    for (int j = 7; j >= 0; j--) {
      int i0 = ((2 * j) << 10) + t;
      mi = (dist[j].y == tmax) ? i0 + 1024 : mi;
      mi = (dist[j].x == tmax) ? i0 : mi;
    }
    // wave max via DPP -> lane 63, broadcast via readlane
    float wv = tmax;
    DPP_MAX(wv, 0x111);
    DPP_MAX(wv, 0x112);
    DPP_MAX(wv, 0x114);
    DPP_MAX(wv, 0x118);
    DPP_MAX(wv, 0x142);
    DPP_MAX(wv, 0x143);
    float swv = __int_as_float(
        __builtin_amdgcn_readlane(__float_as_int(wv), 63));
    // qualified lanes contribute ~mi; wave-max of ~mi = ~(min mi)
    unsigned umi = (tmax == swv) ? ~(unsigned)mi : 0u;
    DPP_UMAX(umi, 0x111);
    DPP_UMAX(umi, 0x112);
    DPP_UMAX(umi, 0x114);
    DPP_UMAX(umi, 0x118);
    DPP_UMAX(umi, 0x142);
    DPP_UMAX(umi, 0x143);
    if ((t & 63) == 63) {            // one u64 atomic per wave
      unsigned long long key =
          ((unsigned long long)__float_as_uint(fmaxf(swv, 0.f)) << 32) |
          (unsigned long long)umi;
      atomicMax(&gkey[k % 3], key);
    }
    __syncthreads();                 // the ONLY barrier per step
    unsigned long long bk = gkey[k % 3];
    if (t == 0) gkey[(k + 2) % 3] = 0ull;  // post-barrier reset (audited)
    far = (int)(~(unsigned)bk);
  }
}

// ---- K2: GEMM1 over LOCAL channels only + per-batch glob base + BN1 sums --
// h1 = local_feat @ W1_loc + (gf@W1_glob + b1)   [glob part precomputed in K1]
__global__ __launch_bounds__(384) void k_gemm1(const float* p,
                                               const float* Wc,
                                               const float* bc,
                                               float* ws) {
  __shared__ __align__(16) float ct[HALF * 8];
  int t = threadIdx.x;
  int row0 = blockIdx.x * 8;
  int b = row0 >> 8;                 // 8 rows never span a batch (256 | 8)
  const int* fidx = (const int*)(ws + OFF_IDX);
  for (int sI = t; sI < 8 * HALF; sI += 384) {  // stage sampled local_feat
    int r = sI / HALF, co = sI % HALF;
    int row = row0 + r;
    int i = fidx[row];
    const float* pp = p + (b * PN + i) * 3;
    float val = bc[co];
    val = fmaf(pp[0], Wc[co], val);
    val = fmaf(pp[1], Wc[HALF + co], val);
    val = fmaf(pp[2], Wc[2 * HALF + co], val);
    ct[co * 8 + r] = val;
  }
  __syncthreads();
  const float* w1t = ws + OFF_W1T;
  float acc[8] = {0.f, 0.f, 0.f, 0.f, 0.f, 0.f, 0.f, 0.f};
  for (int c = 0; c < HALF; c++) {
    float w = w1t[c * HID + t];
    float4 a0 = *(const float4*)(ct + c * 8);
    float4 a1 = *(const float4*)(ct + c * 8 + 4);
    acc[0] = fmaf(a0.x, w, acc[0]); acc[1] = fmaf(a0.y, w, acc[1]);
    acc[2] = fmaf(a0.z, w, acc[2]); acc[3] = fmaf(a0.w, w, acc[3]);
    acc[4] = fmaf(a1.x, w, acc[4]); acc[5] = fmaf(a1.y, w, acc[5]);
    acc[6] = fmaf(a1.z, w, acc[6]); acc[7] = fmaf(a1.w, w, acc[7]);
  }
  float base = ws[OFF_GFW + b * HID + t];  // includes b1 + glob contribution
  float sv = 0.f, sq = 0.f;
#pragma unroll
  for (int r = 0; r < 8; r++) {
    float v = acc[r] + base;
    ws[OFF_H1 + (row0 + r) * HID + t] = v;
    sv += v; sq = fmaf(v, v, sq);
  }
  atomicAdd(&ws[OFF_SUM1 + t], sv);
  atomicAdd(&ws[OFF_SQ1 + t], sq);
}

// ---- K3: GEMM2 with inline BN1 finalize + ReLU on load -------------------
__global__ __launch_bounds__(384) void k_gemm2(const float* b2,
                                               const float* g1,
                                               const float* be1,
                                               float* ws) {
  __shared__ __align__(16) float ht[HID * 8];
  __shared__ float sc1s[HID], sh1s[HID];
  int t = threadIdx.x;
  int row0 = blockIdx.x * 8;
  {                                   // BN1 finalize, redundantly per block
    float m = ws[OFF_SUM1 + t] * (1.f / ROWS);
    float v = ws[OFF_SQ1 + t] * (1.f / ROWS) - m * m;
    float inv = 1.f / sqrtf(v + BN_EPS);
    float sc = inv * g1[t];
    sc1s[t] = sc;
    sh1s[t] = be1[t] - m * sc;
  }
  __syncthreads();
  for (int sI = t; sI < 8 * HID; sI += 384) {
    int r = sI / HID, c = sI % HID;
    float x = fmaf(ws[OFF_H1 + (row0 + r) * HID + c], sc1s[c], sh1s[c]);
    ht[c * 8 + r] = fmaxf(x, 0.f);
  }
  __syncthreads();
  const float* w2t = ws + OFF_W2T;
  float acc[8] = {0.f, 0.f, 0.f, 0.f, 0.f, 0.f, 0.f, 0.f};
  for (int c = 0; c < HID; c++) {
    float w = w2t[c * HID + t];
    float4 a0 = *(const float4*)(ht + c * 8);
    float4 a1 = *(const float4*)(ht + c * 8 + 4);
    acc[0] = fmaf(a0.x, w, acc[0]); acc[1] = fmaf(a0.y, w, acc[1]);
    acc[2] = fmaf(a0.z, w, acc[2]); acc[3] = fmaf(a0.w, w, acc[3]);
    acc[4] = fmaf(a1.x, w, acc[4]); acc[5] = fmaf(a1.y, w, acc[5]);
    acc[6] = fmaf(a1.z, w, acc[6]); acc[7] = fmaf(a1.w, w, acc[7]);
  }
  float bias = b2[t];
  float sv = 0.f, sq = 0.f;
#pragma unroll
  for (int r = 0; r < 8; r++) {
    float v = acc[r] + bias;
    ws[OFF_H2 + (row0 + r) * HID + t] = v;
    sv += v; sq = fmaf(v, v, sq);
  }
  atomicAdd(&ws[OFF_SUM2 + t], sv);
  atomicAdd(&ws[OFF_SQ2 + t], sq);
}

// ---- K4: inline BN2 finalize + affine + ReLU -----------------------------
__global__ __launch_bounds__(256) void k_out(const float* ws, const float* g2,
                                             const float* be2, float* out) {
  int gid = blockIdx.x * 256 + threadIdx.x;
  int i = gid * 4;
  int c = i % HID;                    // multiple of 4
  float4 h  = *(const float4*)(ws + OFF_H2 + i);
  float4 s2 = *(const float4*)(ws + OFF_SUM2 + c);
  float4 q2 = *(const float4*)(ws + OFF_SQ2 + c);
  float4 gv = *(const float4*)(g2 + c);
  float4 bv = *(const float4*)(be2 + c);
  float4 r;
#define BN2(comp) {                                                  \
    float m  = s2.comp * (1.f / ROWS);                               \
    float v  = q2.comp * (1.f / ROWS) - m * m;                       \
    float sc = (1.f / sqrtf(v + BN_EPS)) * gv.comp;                  \
    float sh = bv.comp - m * sc;                                     \
    r.comp = fmaxf(fmaf(h.comp, sc, sh), 0.f); }
  BN2(x) BN2(y) BN2(z) BN2(w)
#undef BN2
  ((float4*)out)[gid] = r;
}

extern "C" void kernel_launch(void* const* d_in, const int* in_sizes, int n_in,
                              void* d_out, int out_size, void* d_ws, size_t ws_size,
                              hipStream_t stream) {
  const float* p   = (const float*)d_in[0];
  // d_in[1] = N (int scalar, always 256)
  const float* pf  = (const float*)d_in[2];
  const float* Wf  = (const float*)d_in[3];
  const float* bfe = (const float*)d_in[4];
  const float* Wc  = (const float*)d_in[5];
  const float* bc  = (const float*)d_in[6];
  const float* W1  = (const float*)d_in[7];
  const float* b1  = (const float*)d_in[8];
  const float* g1  = (const float*)d_in[9];
  const float* be1 = (const float*)d_in[10];
  const float* W2  = (const float*)d_in[11];
  const float* b2  = (const float*)d_in[12];
  const float* g2  = (const float*)d_in[13];
  const float* be2 = (const float*)d_in[14];
  float* ws = (float*)d_ws;

  hipLaunchKernelGGL(k_main,  dim3(33),  dim3(1024), 0, stream,
                     p, Wc, pf, Wf, bfe, W1, b1, W2, ws);
  hipLaunchKernelGGL(k_gemm1, dim3(256), dim3(384), 0, stream, p, Wc, bc, ws);
  hipLaunchKernelGGL(k_gemm2, dim3(256), dim3(384), 0, stream, b2, g1, be1, ws);
  hipLaunchKernelGGL(k_out,   dim3(768), dim3(256), 0, stream,
                     ws, g2, be2, (float*)d_out);
}

// Round 10
// 504.355 us; speedup vs baseline: 1.0459x; 1.0459x over previous
//
#include <hip/hip_runtime.h>

#define BATCH 8
#define PN    16384
#define NSAMP 256
#define KDIM  512
#define HID   384
#define HALF  192
#define CIN   576   // HID + HALF
#define ROWS  2048  // BATCH * NSAMP
#define BN_EPS 1e-5f

// workspace offsets (in floats)
#define OFF_GF   0
#define OFF_W1T  3072      /* local-part transpose: [192][384] = 73728 */
#define OFF_GFW  76800     /* per-batch gf@W1_glob + b1: [8][384] */
#define OFF_W2T  224256
#define OFF_IDX  371712    /* 2048 ints */
#define OFF_H1   373760    /* ALSO: FPS q-array [8][16384] float4, dead before gemm1 writes H1 */
#define OFF_H2   1160192
#define OFF_SUM1 1946624
#define OFF_SQ1  1947008
#define OFF_SUM2 1947392
#define OFF_SQ2  1947776

typedef float v2f __attribute__((ext_vector_type(2)));

// one DPP max step: v = max(v, dpp_move(v)); masked lanes read 0 (identity
// for dist >= 0). Sequence hardware-verified in earlier passing rounds.
#define DPP_MAX(v, ctrl)                                                   \
  v = fmaxf(v, __int_as_float(__builtin_amdgcn_update_dpp(                 \
          0, __float_as_int(v), (ctrl), 0xf, 0xf, true)))

// ---- K1: fused FPS (blocks 0..7) + prep (blocks 8..32) --------------------
// R8-proven structure (best measured: k_main ~367 us). FPS on 192-dim
// local_feat == FPS on 3-dim p under metric G = Wc Wc^T = LL^T.
// q = L^T p; d(i,c) = n_i - 2<q_i,q_c> + n_c, n=|q|^2 in regs.
// Step chain: qc load -> dist -> DPP wave max -> lane63 atomicMax(f32 bits)
// into gb[par] -> B1 -> gmax = one LDS read -> rare claim (descending
// predicated scan + atomicMin widx = jnp.argmax first-index) -> B2 ->
// far registered. Double-buffered gb/widx resets barrier-separated (audited).
__global__ __launch_bounds__(1024)
void k_main(const float* p, const float* Wc,
            const float* pf, const float* Wf,
            const float* bfe, const float* W1,
            const float* b1v, const float* W2,
            float* ws) {
  __shared__ float s[KDIM];
  __shared__ float Msh[6];
  __shared__ unsigned gb[2];
  __shared__ int widx[2];
  int blk = blockIdx.x, t = threadIdx.x;

  if (blk >= 8) {                    // ---- prep work, hidden under FPS ----
    if (blk < 16) {                  // W1t_loc[c][o] = W1[o][HID + c], c<192
      for (int sI = (blk - 8) * 1024 + t; sI < HID * HALF; sI += 8192) {
        int o = sI / HALF, c = sI % HALF;
        ws[OFF_W1T + c * HID + o] = W1[o * CIN + HID + c];
      }
    } else if (blk < 24) {           // W2t[c][o] = W2[o][c]
      for (int sI = (blk - 16) * 1024 + t; sI < HID * HID; sI += 8192) {
        int o = sI / HID, c = sI % HID;
        ws[OFF_W2T + c * HID + o] = W2[sI];
      }
    } else if (blk < 32) {           // gf[b] = pf[b]@W_feat + b_feat ; then
      int b = blk - 24;              // gfW[b] = b1 + gf[b]@W1_glob (per-batch)
      if (t < KDIM) s[t] = pf[b * KDIM + t];
      __syncthreads();
      float acc = 0.f;
      if (t < HID) {
        acc = bfe[t];
        for (int k = 0; k < KDIM; k++) acc = fmaf(s[k], Wf[k * HID + t], acc);
        ws[OFF_GF + b * HID + t] = acc;
      }
      __syncthreads();               // all reads of s done
      if (t < HID) s[t] = acc;       // reuse s[0..383] for gf
      __syncthreads();
      if (t < HID) {
        float g = b1v[t];
        const float* w1row = W1 + t * CIN;   // row o=t, glob channels 0..383
        for (int c = 0; c < HID; c++) g = fmaf(s[c], w1row[c], g);
        ws[OFF_GFW + b * HID + t] = g;
      }
    } else {                         // zero BN sums (contiguous 1536 floats)
      for (int i = t; i < 1536; i += 1024) ws[OFF_SUM1 + i] = 0.f;
    }
    return;
  }

  // ---- FPS, one batch per block ----
  int b = blk;
  int* idx_out = (int*)(ws + OFF_IDX);

  if (t < 64) {                      // G (3x3) in fp64 + Cholesky, wave 0
    double g0 = 0, g1 = 0, g2 = 0, g3 = 0, g4 = 0, g5 = 0;
    for (int k = t; k < HALF; k += 64) {
      double w0 = (double)Wc[k];
      double w1 = (double)Wc[HALF + k];
      double w2 = (double)Wc[2 * HALF + k];
      g0 += w0 * w0; g1 += w0 * w1; g2 += w0 * w2;
      g3 += w1 * w1; g4 += w1 * w2; g5 += w2 * w2;
    }
    for (int off = 32; off; off >>= 1) {
      g0 += __shfl_down(g0, off, 64); g1 += __shfl_down(g1, off, 64);
      g2 += __shfl_down(g2, off, 64); g3 += __shfl_down(g3, off, 64);
      g4 += __shfl_down(g4, off, 64); g5 += __shfl_down(g5, off, 64);
    }
    if (t == 0) {
      double l00 = sqrt(g0);
      double l10 = g1 / l00, l20 = g2 / l00;
      double l11 = sqrt(g3 - l10 * l10);
      double l21 = (g4 - l10 * l20) / l11;
      double l22 = sqrt(g5 - l20 * l20 - l21 * l21);
      Msh[0] = (float)l00; Msh[1] = (float)l10; Msh[2] = (float)l20;
      Msh[3] = (float)l11; Msh[4] = (float)l21; Msh[5] = (float)l22;
    }
  }
  __syncthreads();
  float m00 = Msh[0], m10 = Msh[1], m20 = Msh[2];
  float m11 = Msh[3], m21 = Msh[4], m22 = Msh[5];

  const float* pb = p + b * PN * 3;
  float4* qws = (float4*)(ws + OFF_H1) + b * PN;  // staged {q, |q|^2}
  // ownership: pair j holds global points i0=(2j)*1024+t and i1=i0+1024
  v2f qx[8], qy[8], qz[8], nq[8], dist[8];
#pragma unroll
  for (int j = 0; j < 8; j++) {
    int i0 = ((2 * j) << 10) + t;
    int i1 = i0 + 1024;
    float x0 = pb[i0 * 3], y0 = pb[i0 * 3 + 1], z0 = pb[i0 * 3 + 2];
    float x1 = pb[i1 * 3], y1 = pb[i1 * 3 + 1], z1 = pb[i1 * 3 + 2];
    qx[j] = (v2f){fmaf(m00, x0, fmaf(m10, y0, m20 * z0)),
                  fmaf(m00, x1, fmaf(m10, y1, m20 * z1))};
    qy[j] = (v2f){fmaf(m11, y0, m21 * z0), fmaf(m11, y1, m21 * z1)};
    qz[j] = (v2f){m22 * z0, m22 * z1};
    nq[j] = __builtin_elementwise_fma(
        qx[j], qx[j],
        __builtin_elementwise_fma(qy[j], qy[j], qz[j] * qz[j]));
    dist[j] = (v2f){1e10f, 1e10f};
    qws[i0] = make_float4(qx[j].x, qy[j].x, qz[j].x, nq[j].x);
    qws[i1] = make_float4(qx[j].y, qy[j].y, qz[j].y, nq[j].y);
  }

  if (t == 0) {
    widx[0] = 0x7fffffff; widx[1] = 0x7fffffff;
    gb[0] = 0u; gb[1] = 0u;
  }
  __syncthreads();                   // q-array + seeds visible to block

  int far = 0;                       // step-0 selection (jnp FPS starts at 0)
  int par = 0;
  for (int k = 0; k < NSAMP; k++) {
    float4 qc = qws[far];            // one uniform b128 load (L2)
    float cx2 = -2.f * qc.x, cy2 = -2.f * qc.y, cz2 = -2.f * qc.z;
    v2f cxv = (v2f){cx2, cx2}, cyv = (v2f){cy2, cy2}, czv = (v2f){cz2, cz2};
    v2f ncv = (v2f){qc.w, qc.w};
#pragma unroll
    for (int j = 0; j < 8; j++) {    // d = n_i - 2<q,c> + n_c, packed
      v2f base = nq[j] + ncv;
      v2f d = __builtin_elementwise_fma(
          qx[j], cxv,
          __builtin_elementwise_fma(qy[j], cyv,
              __builtin_elementwise_fma(qz[j], czv, base)));
      dist[j] = __builtin_elementwise_min(dist[j], d);
    }
    if (t == 0) {                    // off the step-entry critical path
      idx_out[b * NSAMP + k] = far;  // scan emits pre-update far
      widx[par] = 0x7fffffff;        // writers are post-B1 (safe)
      gb[par ^ 1] = 0u;              // readers done pre-B2(k-1); writers post-B2(k)
    }
    // per-thread max of 16 (packed tree)
    v2f t0v = __builtin_elementwise_max(dist[0], dist[1]);
    v2f t1v = __builtin_elementwise_max(dist[2], dist[3]);
    v2f t2v = __builtin_elementwise_max(dist[4], dist[5]);
    v2f t3v = __builtin_elementwise_max(dist[6], dist[7]);
    t0v = __builtin_elementwise_max(t0v, t1v);
    t2v = __builtin_elementwise_max(t2v, t3v);
    t0v = __builtin_elementwise_max(t0v, t2v);
    float tmax = fmaxf(t0v.x, t0v.y);
    // wave max via DPP (row_shr 1/2/4/8, row_bcast 15/31) -> lane 63
    float wv = tmax;
    DPP_MAX(wv, 0x111);
    DPP_MAX(wv, 0x112);
    DPP_MAX(wv, 0x114);
    DPP_MAX(wv, 0x118);
    DPP_MAX(wv, 0x142);
    DPP_MAX(wv, 0x143);
    if ((t & 63) == 63)              // f32>=0 bits are order-monotone
      atomicMax(&gb[par], __float_as_uint(fmaxf(wv, 0.f)));
    __syncthreads();                 // barrier 1: gb[par] final
    float gmax = __uint_as_float(gb[par]);
    if (tmax == gmax) {              // rare claim: index-only scan
      // independent predicated selects, DESCENDING index order:
      // last executed write = smallest matching index (first-index tiebreak)
      int mi = 0x7fffffff;
#pragma unroll
      for (int j = 7; j >= 0; j--) {
        int i0 = ((2 * j) << 10) + t;
        mi = (dist[j].y == gmax) ? i0 + 1024 : mi;
        mi = (dist[j].x == gmax) ? i0 : mi;
      }
      atomicMin(&widx[par], mi);     // smallest global index wins => argmax
    }
    __syncthreads();                 // barrier 2: selection resolved
    far = widx[par];                 // registered for next iteration
    par ^= 1;
  }
}

// ---- K2: GEMM1 over LOCAL channels only + per-batch glob base + BN1 sums --
// h1 = local_feat @ W1_loc + (gf@W1_glob + b1)   [glob part precomputed in K1]
// 4-row tiles x 512 blocks: 2 blocks/CU (3 waves/SIMD) for latency hiding;
// one ds_read_b128 covers the whole row-tile per c.
__global__ __launch_bounds__(384) void k_gemm1(const float* p,
                                               const float* Wc,
                                               const float* bc,
                                               float* ws) {
  __shared__ __align__(16) float ct[HALF * 4];
  int t = threadIdx.x;
  int row0 = blockIdx.x * 4;
  int b = row0 >> 8;                 // 4 rows never span a batch (256 | 4)
  const int* fidx = (const int*)(ws + OFF_IDX);
  for (int sI = t; sI < 4 * HALF; sI += 384) {  // stage sampled local_feat
    int r = sI / HALF, co = sI % HALF;
    int row = row0 + r;
    int i = fidx[row];
    const float* pp = p + (b * PN + i) * 3;
    float val = bc[co];
    val = fmaf(pp[0], Wc[co], val);
    val = fmaf(pp[1], Wc[HALF + co], val);
    val = fmaf(pp[2], Wc[2 * HALF + co], val);
    ct[co * 4 + r] = val;
  }
  __syncthreads();
  const float* w1t = ws + OFF_W1T;
  float acc[4] = {0.f, 0.f, 0.f, 0.f};
  for (int c = 0; c < HALF; c++) {
    float w = w1t[c * HID + t];
    float4 a = *(const float4*)(ct + c * 4);
    acc[0] = fmaf(a.x, w, acc[0]); acc[1] = fmaf(a.y, w, acc[1]);
    acc[2] = fmaf(a.z, w, acc[2]); acc[3] = fmaf(a.w, w, acc[3]);
  }
  float base = ws[OFF_GFW + b * HID + t];  // includes b1 + glob contribution
  float sv = 0.f, sq = 0.f;
#pragma unroll
  for (int r = 0; r < 4; r++) {
    float v = acc[r] + base;
    ws[OFF_H1 + (row0 + r) * HID + t] = v;
    sv += v; sq = fmaf(v, v, sq);
  }
  atomicAdd(&ws[OFF_SUM1 + t], sv);
  atomicAdd(&ws[OFF_SQ1 + t], sq);
}

// ---- K3: GEMM2 with inline BN1 finalize + ReLU on load -------------------
// 4-row tiles x 512 blocks (same occupancy rationale as K2).
__global__ __launch_bounds__(384) void k_gemm2(const float* b2,
                                               const float* g1,
                                               const float* be1,
                                               float* ws) {
  __shared__ __align__(16) float ht[HID * 4];
  __shared__ float sc1s[HID], sh1s[HID];
  int t = threadIdx.x;
  int row0 = blockIdx.x * 4;
  {                                   // BN1 finalize, redundantly per block
    float m = ws[OFF_SUM1 + t] * (1.f / ROWS);
    float v = ws[OFF_SQ1 + t] * (1.f / ROWS) - m * m;
    float inv = 1.f / sqrtf(v + BN_EPS);
    float sc = inv * g1[t];
    sc1s[t] = sc;
    sh1s[t] = be1[t] - m * sc;
  }
  __syncthreads();
  for (int sI = t; sI < 4 * HID; sI += 384) {
    int r = sI / HID, c = sI % HID;
    float x = fmaf(ws[OFF_H1 + (row0 + r) * HID + c], sc1s[c], sh1s[c]);
    ht[c * 4 + r] = fmaxf(x, 0.f);
  }
  __syncthreads();
  const float* w2t = ws + OFF_W2T;
  float acc[4] = {0.f, 0.f, 0.f, 0.f};
  for (int c = 0; c < HID; c++) {
    float w = w2t[c * HID + t];
    float4 a = *(const float4*)(ht + c * 4);
    acc[0] = fmaf(a.x, w, acc[0]); acc[1] = fmaf(a.y, w, acc[1]);
    acc[2] = fmaf(a.z, w, acc[2]); acc[3] = fmaf(a.w, w, acc[3]);
  }
  float bias = b2[t];
  float sv = 0.f, sq = 0.f;
#pragma unroll
  for (int r = 0; r < 4; r++) {
    float v = acc[r] + bias;
    ws[OFF_H2 + (row0 + r) * HID + t] = v;
    sv += v; sq = fmaf(v, v, sq);
  }
  atomicAdd(&ws[OFF_SUM2 + t], sv);
  atomicAdd(&ws[OFF_SQ2 + t], sq);
}

// ---- K4: inline BN2 finalize + affine + ReLU -----------------------------
__global__ __launch_bounds__(256) void k_out(const float* ws, const float* g2,
                                             const float* be2, float* out) {
  int gid = blockIdx.x * 256 + threadIdx.x;
  int i = gid * 4;
  int c = i % HID;                    // multiple of 4
  float4 h  = *(const float4*)(ws + OFF_H2 + i);
  float4 s2 = *(const float4*)(ws + OFF_SUM2 + c);
  float4 q2 = *(const float4*)(ws + OFF_SQ2 + c);
  float4 gv = *(const float4*)(g2 + c);
  float4 bv = *(const float4*)(be2 + c);
  float4 r;
#define BN2(comp) {                                                  \
    float m  = s2.comp * (1.f / ROWS);                               \
    float v  = q2.comp * (1.f / ROWS) - m * m;                       \
    float sc = (1.f / sqrtf(v + BN_EPS)) * gv.comp;                  \
    float sh = bv.comp - m * sc;                                     \
    r.comp = fmaxf(fmaf(h.comp, sc, sh), 0.f); }
  BN2(x) BN2(y) BN2(z) BN2(w)
#undef BN2
  ((float4*)out)[gid] = r;
}

extern "C" void kernel_launch(void* const* d_in, const int* in_sizes, int n_in,
                              void* d_out, int out_size, void* d_ws, size_t ws_size,
                              hipStream_t stream) {
  const float* p   = (const float*)d_in[0];
  // d_in[1] = N (int scalar, always 256)
  const float* pf  = (const float*)d_in[2];
  const float* Wf  = (const float*)d_in[3];
  const float* bfe = (const float*)d_in[4];
  const float* Wc  = (const float*)d_in[5];
  const float* bc  = (const float*)d_in[6];
  const float* W1  = (const float*)d_in[7];
  const float* b1  = (const float*)d_in[8];
  const float* g1  = (const float*)d_in[9];
  const float* be1 = (const float*)d_in[10];
  const float* W2  = (const float*)d_in[11];
  const float* b2  = (const float*)d_in[12];
  const float* g2  = (const float*)d_in[13];
  const float* be2 = (const float*)d_in[14];
  float* ws = (float*)d_ws;

  hipLaunchKernelGGL(k_main,  dim3(33),  dim3(1024), 0, stream,
                     p, Wc, pf, Wf, bfe, W1, b1, W2, ws);
  hipLaunchKernelGGL(k_gemm1, dim3(512), dim3(384), 0, stream, p, Wc, bc, ws);
  hipLaunchKernelGGL(k_gemm2, dim3(512), dim3(384), 0, stream, b2, g1, be1, ws);
  hipLaunchKernelGGL(k_out,   dim3(768), dim3(256), 0, stream,
                     ws, g2, be2, (float*)d_out);
}

// Round 11
// 496.184 us; speedup vs baseline: 1.0631x; 1.0165x over previous
//
#include <hip/hip_runtime.h>

#define BATCH 8
#define PN    16384
#define NSAMP 256
#define KDIM  512
#define HID   384
#define HALF  192
#define CIN   576   // HID + HALF
#define ROWS  2048  // BATCH * NSAMP
#define BN_EPS 1e-5f

// workspace offsets (in floats)
#define OFF_GF   0
#define OFF_W1T  3072      /* local-part transpose: [192][384] = 73728 */
#define OFF_GFW  76800     /* per-batch gf@W1_glob + b1: [8][384] */
#define OFF_W2T  224256
#define OFF_IDX  371712    /* 2048 ints */
#define OFF_H1   373760    /* ALSO: FPS q-array [8][16384] float4, dead before gemm1 writes H1 */
#define OFF_H2   1160192
#define OFF_SUM1 1946624
#define OFF_SQ1  1947008
#define OFF_SUM2 1947392
#define OFF_SQ2  1947776

typedef float v2f __attribute__((ext_vector_type(2)));

// one DPP max step: v = max(v, dpp_move(v)); masked lanes read 0 (identity
// for dist >= 0). Sequence hardware-verified in earlier passing rounds.
#define DPP_MAX(v, ctrl)                                                   \
  v = fmaxf(v, __int_as_float(__builtin_amdgcn_update_dpp(                 \
          0, __float_as_int(v), (ctrl), 0xf, 0xf, true)))

// ---- K1: fused FPS (blocks 0..7) + prep (blocks 8..32) --------------------
// R8-proven structure (session-best: k_main ~367 us, total ~495.6 us).
// FPS on 192-dim local_feat == FPS on 3-dim p under metric G = Wc Wc^T = LL^T.
// q = L^T p; d(i,c) = n_i - 2<q_i,q_c> + n_c, n=|q|^2 in regs.
// Step chain: qc load -> dist -> DPP wave max -> lane63 atomicMax(f32 bits)
// into gb[par] -> B1 -> gmax = one LDS read -> rare claim (descending
// predicated scan + atomicMin widx = jnp.argmax first-index) -> B2 ->
// far registered. Double-buffered gb/widx resets barrier-separated (audited).
// Two barriers/step is structurally minimal: claims must be barrier-separated
// from reads; fusing value+index pre-barrier costs all-wave issue (R9: +27us).
__global__ __launch_bounds__(1024)
void k_main(const float* p, const float* Wc,
            const float* pf, const float* Wf,
            const float* bfe, const float* W1,
            const float* b1v, const float* W2,
            float* ws) {
  __shared__ float s[KDIM];
  __shared__ float Msh[6];
  __shared__ unsigned gb[2];
  __shared__ int widx[2];
  int blk = blockIdx.x, t = threadIdx.x;

  if (blk >= 8) {                    // ---- prep work, hidden under FPS ----
    if (blk < 16) {                  // W1t_loc[c][o] = W1[o][HID + c], c<192
      for (int sI = (blk - 8) * 1024 + t; sI < HID * HALF; sI += 8192) {
        int o = sI / HALF, c = sI % HALF;
        ws[OFF_W1T + c * HID + o] = W1[o * CIN + HID + c];
      }
    } else if (blk < 24) {           // W2t[c][o] = W2[o][c]
      for (int sI = (blk - 16) * 1024 + t; sI < HID * HID; sI += 8192) {
        int o = sI / HID, c = sI % HID;
        ws[OFF_W2T + c * HID + o] = W2[sI];
      }
    } else if (blk < 32) {           // gf[b] = pf[b]@W_feat + b_feat ; then
      int b = blk - 24;              // gfW[b] = b1 + gf[b]@W1_glob (per-batch)
      if (t < KDIM) s[t] = pf[b * KDIM + t];
      __syncthreads();
      float acc = 0.f;
      if (t < HID) {
        acc = bfe[t];
        for (int k = 0; k < KDIM; k++) acc = fmaf(s[k], Wf[k * HID + t], acc);
        ws[OFF_GF + b * HID + t] = acc;
      }
      __syncthreads();               // all reads of s done
      if (t < HID) s[t] = acc;       // reuse s[0..383] for gf
      __syncthreads();
      if (t < HID) {
        float g = b1v[t];
        const float* w1row = W1 + t * CIN;   // row o=t, glob channels 0..383
        for (int c = 0; c < HID; c++) g = fmaf(s[c], w1row[c], g);
        ws[OFF_GFW + b * HID + t] = g;
      }
    } else {                         // zero BN sums (contiguous 1536 floats)
      for (int i = t; i < 1536; i += 1024) ws[OFF_SUM1 + i] = 0.f;
    }
    return;
  }

  // ---- FPS, one batch per block ----
  int b = blk;
  int* idx_out = (int*)(ws + OFF_IDX);

  if (t < 64) {                      // G (3x3) in fp64 + Cholesky, wave 0
    double g0 = 0, g1 = 0, g2 = 0, g3 = 0, g4 = 0, g5 = 0;
    for (int k = t; k < HALF; k += 64) {
      double w0 = (double)Wc[k];
      double w1 = (double)Wc[HALF + k];
      double w2 = (double)Wc[2 * HALF + k];
      g0 += w0 * w0; g1 += w0 * w1; g2 += w0 * w2;
      g3 += w1 * w1; g4 += w1 * w2; g5 += w2 * w2;
    }
    for (int off = 32; off; off >>= 1) {
      g0 += __shfl_down(g0, off, 64); g1 += __shfl_down(g1, off, 64);
      g2 += __shfl_down(g2, off, 64); g3 += __shfl_down(g3, off, 64);
      g4 += __shfl_down(g4, off, 64); g5 += __shfl_down(g5, off, 64);
    }
    if (t == 0) {
      double l00 = sqrt(g0);
      double l10 = g1 / l00, l20 = g2 / l00;
      double l11 = sqrt(g3 - l10 * l10);
      double l21 = (g4 - l10 * l20) / l11;
      double l22 = sqrt(g5 - l20 * l20 - l21 * l21);
      Msh[0] = (float)l00; Msh[1] = (float)l10; Msh[2] = (float)l20;
      Msh[3] = (float)l11; Msh[4] = (float)l21; Msh[5] = (float)l22;
    }
  }
  __syncthreads();
  float m00 = Msh[0], m10 = Msh[1], m20 = Msh[2];
  float m11 = Msh[3], m21 = Msh[4], m22 = Msh[5];

  const float* pb = p + b * PN * 3;
  float4* qws = (float4*)(ws + OFF_H1) + b * PN;  // staged {q, |q|^2}
  // ownership: pair j holds global points i0=(2j)*1024+t and i1=i0+1024
  v2f qx[8], qy[8], qz[8], nq[8], dist[8];
#pragma unroll
  for (int j = 0; j < 8; j++) {
    int i0 = ((2 * j) << 10) + t;
    int i1 = i0 + 1024;
    float x0 = pb[i0 * 3], y0 = pb[i0 * 3 + 1], z0 = pb[i0 * 3 + 2];
    float x1 = pb[i1 * 3], y1 = pb[i1 * 3 + 1], z1 = pb[i1 * 3 + 2];
    qx[j] = (v2f){fmaf(m00, x0, fmaf(m10, y0, m20 * z0)),
                  fmaf(m00, x1, fmaf(m10, y1, m20 * z1))};
    qy[j] = (v2f){fmaf(m11, y0, m21 * z0), fmaf(m11, y1, m21 * z1)};
    qz[j] = (v2f){m22 * z0, m22 * z1};
    nq[j] = __builtin_elementwise_fma(
        qx[j], qx[j],
        __builtin_elementwise_fma(qy[j], qy[j], qz[j] * qz[j]));
    dist[j] = (v2f){1e10f, 1e10f};
    qws[i0] = make_float4(qx[j].x, qy[j].x, qz[j].x, nq[j].x);
    qws[i1] = make_float4(qx[j].y, qy[j].y, qz[j].y, nq[j].y);
  }

  if (t == 0) {
    widx[0] = 0x7fffffff; widx[1] = 0x7fffffff;
    gb[0] = 0u; gb[1] = 0u;
  }
  __syncthreads();                   // q-array + seeds visible to block

  int far = 0;                       // step-0 selection (jnp FPS starts at 0)
  int par = 0;
  for (int k = 0; k < NSAMP; k++) {
    float4 qc = qws[far];            // one uniform b128 load (L2)
    float cx2 = -2.f * qc.x, cy2 = -2.f * qc.y, cz2 = -2.f * qc.z;
    v2f cxv = (v2f){cx2, cx2}, cyv = (v2f){cy2, cy2}, czv = (v2f){cz2, cz2};
    v2f ncv = (v2f){qc.w, qc.w};
#pragma unroll
    for (int j = 0; j < 8; j++) {    // d = n_i - 2<q,c> + n_c, packed
      v2f base = nq[j] + ncv;
      v2f d = __builtin_elementwise_fma(
          qx[j], cxv,
          __builtin_elementwise_fma(qy[j], cyv,
              __builtin_elementwise_fma(qz[j], czv, base)));
      dist[j] = __builtin_elementwise_min(dist[j], d);
    }
    if (t == 0) {                    // off the step-entry critical path
      idx_out[b * NSAMP + k] = far;  // scan emits pre-update far
      widx[par] = 0x7fffffff;        // writers are post-B1 (safe)
      gb[par ^ 1] = 0u;              // readers done pre-B2(k-1); writers post-B2(k)
    }
    // per-thread max of 16 (packed tree)
    v2f t0v = __builtin_elementwise_max(dist[0], dist[1]);
    v2f t1v = __builtin_elementwise_max(dist[2], dist[3]);
    v2f t2v = __builtin_elementwise_max(dist[4], dist[5]);
    v2f t3v = __builtin_elementwise_max(dist[6], dist[7]);
    t0v = __builtin_elementwise_max(t0v, t1v);
    t2v = __builtin_elementwise_max(t2v, t3v);
    t0v = __builtin_elementwise_max(t0v, t2v);
    float tmax = fmaxf(t0v.x, t0v.y);
    // wave max via DPP (row_shr 1/2/4/8, row_bcast 15/31) -> lane 63
    float wv = tmax;
    DPP_MAX(wv, 0x111);
    DPP_MAX(wv, 0x112);
    DPP_MAX(wv, 0x114);
    DPP_MAX(wv, 0x118);
    DPP_MAX(wv, 0x142);
    DPP_MAX(wv, 0x143);
    if ((t & 63) == 63)              // f32>=0 bits are order-monotone
      atomicMax(&gb[par], __float_as_uint(fmaxf(wv, 0.f)));
    __syncthreads();                 // barrier 1: gb[par] final
    float gmax = __uint_as_float(gb[par]);
    if (tmax == gmax) {              // rare claim: index-only scan
      // independent predicated selects, DESCENDING index order:
      // last executed write = smallest matching index (first-index tiebreak)
      int mi = 0x7fffffff;
#pragma unroll
      for (int j = 7; j >= 0; j--) {
        int i0 = ((2 * j) << 10) + t;
        mi = (dist[j].y == gmax) ? i0 + 1024 : mi;
        mi = (dist[j].x == gmax) ? i0 : mi;
      }
      atomicMin(&widx[par], mi);     // smallest global index wins => argmax
    }
    __syncthreads();                 // barrier 2: selection resolved
    far = widx[par];                 // registered for next iteration
    par ^= 1;
  }
}

// ---- K2: GEMM1 over LOCAL channels only + per-batch glob base + BN1 sums --
// h1 = local_feat @ W1_loc + (gf@W1_glob + b1)   [glob part precomputed in K1]
// 8-row tiles x 256 blocks: measured-best tail config (R8; 4-row/512-block
// variant regressed ~10us from doubled per-block fixed costs).
__global__ __launch_bounds__(384) void k_gemm1(const float* p,
                                               const float* Wc,
                                               const float* bc,
                                               float* ws) {
  __shared__ __align__(16) float ct[HALF * 8];
  int t = threadIdx.x;
  int row0 = blockIdx.x * 8;
  int b = row0 >> 8;                 // 8 rows never span a batch (256 | 8)
  const int* fidx = (const int*)(ws + OFF_IDX);
  for (int sI = t; sI < 8 * HALF; sI += 384) {  // stage sampled local_feat
    int r = sI / HALF, co = sI % HALF;
    int row = row0 + r;
    int i = fidx[row];
    const float* pp = p + (b * PN + i) * 3;
    float val = bc[co];
    val = fmaf(pp[0], Wc[co], val);
    val = fmaf(pp[1], Wc[HALF + co], val);
    val = fmaf(pp[2], Wc[2 * HALF + co], val);
    ct[co * 8 + r] = val;
  }
  __syncthreads();
  const float* w1t = ws + OFF_W1T;
  float acc[8] = {0.f, 0.f, 0.f, 0.f, 0.f, 0.f, 0.f, 0.f};
  for (int c = 0; c < HALF; c++) {
    float w = w1t[c * HID + t];
    float4 a0 = *(const float4*)(ct + c * 8);
    float4 a1 = *(const float4*)(ct + c * 8 + 4);
    acc[0] = fmaf(a0.x, w, acc[0]); acc[1] = fmaf(a0.y, w, acc[1]);
    acc[2] = fmaf(a0.z, w, acc[2]); acc[3] = fmaf(a0.w, w, acc[3]);
    acc[4] = fmaf(a1.x, w, acc[4]); acc[5] = fmaf(a1.y, w, acc[5]);
    acc[6] = fmaf(a1.z, w, acc[6]); acc[7] = fmaf(a1.w, w, acc[7]);
  }
  float base = ws[OFF_GFW + b * HID + t];  // includes b1 + glob contribution
  float sv = 0.f, sq = 0.f;
#pragma unroll
  for (int r = 0; r < 8; r++) {
    float v = acc[r] + base;
    ws[OFF_H1 + (row0 + r) * HID + t] = v;
    sv += v; sq = fmaf(v, v, sq);
  }
  atomicAdd(&ws[OFF_SUM1 + t], sv);
  atomicAdd(&ws[OFF_SQ1 + t], sq);
}

// ---- K3: GEMM2 with inline BN1 finalize + ReLU on load -------------------
__global__ __launch_bounds__(384) void k_gemm2(const float* b2,
                                               const float* g1,
                                               const float* be1,
                                               float* ws) {
  __shared__ __align__(16) float ht[HID * 8];
  __shared__ float sc1s[HID], sh1s[HID];
  int t = threadIdx.x;
  int row0 = blockIdx.x * 8;
  {                                   // BN1 finalize, redundantly per block
    float m = ws[OFF_SUM1 + t] * (1.f / ROWS);
    float v = ws[OFF_SQ1 + t] * (1.f / ROWS) - m * m;
    float inv = 1.f / sqrtf(v + BN_EPS);
    float sc = inv * g1[t];
    sc1s[t] = sc;
    sh1s[t] = be1[t] - m * sc;
  }
  __syncthreads();
  for (int sI = t; sI < 8 * HID; sI += 384) {
    int r = sI / HID, c = sI % HID;
    float x = fmaf(ws[OFF_H1 + (row0 + r) * HID + c], sc1s[c], sh1s[c]);
    ht[c * 8 + r] = fmaxf(x, 0.f);
  }
  __syncthreads();
  const float* w2t = ws + OFF_W2T;
  float acc[8] = {0.f, 0.f, 0.f, 0.f, 0.f, 0.f, 0.f, 0.f};
  for (int c = 0; c < HID; c++) {
    float w = w2t[c * HID + t];
    float4 a0 = *(const float4*)(ht + c * 8);
    float4 a1 = *(const float4*)(ht + c * 8 + 4);
    acc[0] = fmaf(a0.x, w, acc[0]); acc[1] = fmaf(a0.y, w, acc[1]);
    acc[2] = fmaf(a0.z, w, acc[2]); acc[3] = fmaf(a0.w, w, acc[3]);
    acc[4] = fmaf(a1.x, w, acc[4]); acc[5] = fmaf(a1.y, w, acc[5]);
    acc[6] = fmaf(a1.z, w, acc[6]); acc[7] = fmaf(a1.w, w, acc[7]);
  }
  float bias = b2[t];
  float sv = 0.f, sq = 0.f;
#pragma unroll
  for (int r = 0; r < 8; r++) {
    float v = acc[r] + bias;
    ws[OFF_H2 + (row0 + r) * HID + t] = v;
    sv += v; sq = fmaf(v, v, sq);
  }
  atomicAdd(&ws[OFF_SUM2 + t], sv);
  atomicAdd(&ws[OFF_SQ2 + t], sq);
}

// ---- K4: inline BN2 finalize + affine + ReLU -----------------------------
__global__ __launch_bounds__(256) void k_out(const float* ws, const float* g2,
                                             const float* be2, float* out) {
  int gid = blockIdx.x * 256 + threadIdx.x;
  int i = gid * 4;
  int c = i % HID;                    // multiple of 4
  float4 h  = *(const float4*)(ws + OFF_H2 + i);
  float4 s2 = *(const float4*)(ws + OFF_SUM2 + c);
  float4 q2 = *(const float4*)(ws + OFF_SQ2 + c);
  float4 gv = *(const float4*)(g2 + c);
  float4 bv = *(const float4*)(be2 + c);
  float4 r;
#define BN2(comp) {                                                  \
    float m  = s2.comp * (1.f / ROWS);                               \
    float v  = q2.comp * (1.f / ROWS) - m * m;                       \
    float sc = (1.f / sqrtf(v + BN_EPS)) * gv.comp;                  \
    float sh = bv.comp - m * sc;                                     \
    r.comp = fmaxf(fmaf(h.comp, sc, sh), 0.f); }
  BN2(x) BN2(y) BN2(z) BN2(w)
#undef BN2
  ((float4*)out)[gid] = r;
}

extern "C" void kernel_launch(void* const* d_in, const int* in_sizes, int n_in,
                              void* d_out, int out_size, void* d_ws, size_t ws_size,
                              hipStream_t stream) {
  const float* p   = (const float*)d_in[0];
  // d_in[1] = N (int scalar, always 256)
  const float* pf  = (const float*)d_in[2];
  const float* Wf  = (const float*)d_in[3];
  const float* bfe = (const float*)d_in[4];
  const float* Wc  = (const float*)d_in[5];
  const float* bc  = (const float*)d_in[6];
  const float* W1  = (const float*)d_in[7];
  const float* b1  = (const float*)d_in[8];
  const float* g1  = (const float*)d_in[9];
  const float* be1 = (const float*)d_in[10];
  const float* W2  = (const float*)d_in[11];
  const float* b2  = (const float*)d_in[12];
  const float* g2  = (const float*)d_in[13];
  const float* be2 = (const float*)d_in[14];
  float* ws = (float*)d_ws;

  hipLaunchKernelGGL(k_main,  dim3(33),  dim3(1024), 0, stream,
                     p, Wc, pf, Wf, bfe, W1, b1, W2, ws);
  hipLaunchKernelGGL(k_gemm1, dim3(256), dim3(384), 0, stream, p, Wc, bc, ws);
  hipLaunchKernelGGL(k_gemm2, dim3(256), dim3(384), 0, stream, b2, g1, be1, ws);
  hipLaunchKernelGGL(k_out,   dim3(768), dim3(256), 0, stream,
                     ws, g2, be2, (float*)d_out);
}

// Round 12
// 482.948 us; speedup vs baseline: 1.0922x; 1.0274x over previous
//
#include <hip/hip_runtime.h>

#define BATCH 8
#define PN    16384
#define NSAMP 256
#define KDIM  512
#define HID   384
#define HALF  192
#define CIN   576   // HID + HALF
#define ROWS  2048  // BATCH * NSAMP
#define BN_EPS 1e-5f

// workspace offsets (in floats)
#define OFF_GF   0
#define OFF_W1T  3072      /* local-part transpose: [192][384] = 73728 */
#define OFF_GFW  76800     /* per-batch gf@W1_glob + b1: [8][384] */
#define OFF_W2T  224256
#define OFF_IDX  371712    /* 2048 ints */
#define OFF_H1   373760    /* ALSO: FPS q-array [8][16384] float4, dead before gemm1 writes H1 */
#define OFF_H2   1160192
#define OFF_SUM1 1946624
#define OFF_SQ1  1947008
#define OFF_SUM2 1947392
#define OFF_SQ2  1947776

typedef float v2f __attribute__((ext_vector_type(2)));

// one DPP max step: v = max(v, dpp_move(v)); masked lanes read 0 (identity
// for dist >= 0). Sequence hardware-verified in earlier passing rounds.
#define DPP_MAX(v, ctrl)                                                   \
  v = fmaxf(v, __int_as_float(__builtin_amdgcn_update_dpp(                 \
          0, __float_as_int(v), (ctrl), 0xf, 0xf, true)))

// ---- K1: fused FPS (blocks 0..7) + prep (blocks 8..32) --------------------
// R8-proven structure (session-best; byte-identical here). FPS on 192-dim
// local_feat == FPS on 3-dim p under metric G = Wc Wc^T = LL^T.
// q = L^T p; d(i,c) = n_i - 2<q_i,q_c> + n_c, n=|q|^2 in regs.
// Step chain: qc load -> dist -> DPP wave max -> lane63 atomicMax(f32 bits)
// into gb[par] -> B1 -> gmax = one LDS read -> rare claim (descending
// predicated scan + atomicMin widx = jnp.argmax first-index) -> B2 ->
// far registered. Double-buffered gb/widx resets barrier-separated (audited).
// Two barriers/step is structurally minimal: claims must be barrier-separated
// from reads; fusing value+index pre-barrier costs all-wave issue (R9: +27us).
__global__ __launch_bounds__(1024)
void k_main(const float* p, const float* Wc,
            const float* pf, const float* Wf,
            const float* bfe, const float* W1,
            const float* b1v, const float* W2,
            float* ws) {
  __shared__ float s[KDIM];
  __shared__ float Msh[6];
  __shared__ unsigned gb[2];
  __shared__ int widx[2];
  int blk = blockIdx.x, t = threadIdx.x;

  if (blk >= 8) {                    // ---- prep work, hidden under FPS ----
    if (blk < 16) {                  // W1t_loc[c][o] = W1[o][HID + c], c<192
      for (int sI = (blk - 8) * 1024 + t; sI < HID * HALF; sI += 8192) {
        int o = sI / HALF, c = sI % HALF;
        ws[OFF_W1T + c * HID + o] = W1[o * CIN + HID + c];
      }
    } else if (blk < 24) {           // W2t[c][o] = W2[o][c]
      for (int sI = (blk - 16) * 1024 + t; sI < HID * HID; sI += 8192) {
        int o = sI / HID, c = sI % HID;
        ws[OFF_W2T + c * HID + o] = W2[sI];
      }
    } else if (blk < 32) {           // gf[b] = pf[b]@W_feat + b_feat ; then
      int b = blk - 24;              // gfW[b] = b1 + gf[b]@W1_glob (per-batch)
      if (t < KDIM) s[t] = pf[b * KDIM + t];
      __syncthreads();
      float acc = 0.f;
      if (t < HID) {
        acc = bfe[t];
        for (int k = 0; k < KDIM; k++) acc = fmaf(s[k], Wf[k * HID + t], acc);
        ws[OFF_GF + b * HID + t] = acc;
      }
      __syncthreads();               // all reads of s done
      if (t < HID) s[t] = acc;       // reuse s[0..383] for gf
      __syncthreads();
      if (t < HID) {
        float g = b1v[t];
        const float* w1row = W1 + t * CIN;   // row o=t, glob channels 0..383
        for (int c = 0; c < HID; c++) g = fmaf(s[c], w1row[c], g);
        ws[OFF_GFW + b * HID + t] = g;
      }
    } else {                         // zero BN sums (contiguous 1536 floats)
      for (int i = t; i < 1536; i += 1024) ws[OFF_SUM1 + i] = 0.f;
    }
    return;
  }

  // ---- FPS, one batch per block ----
  int b = blk;
  int* idx_out = (int*)(ws + OFF_IDX);

  if (t < 64) {                      // G (3x3) in fp64 + Cholesky, wave 0
    double g0 = 0, g1 = 0, g2 = 0, g3 = 0, g4 = 0, g5 = 0;
    for (int k = t; k < HALF; k += 64) {
      double w0 = (double)Wc[k];
      double w1 = (double)Wc[HALF + k];
      double w2 = (double)Wc[2 * HALF + k];
      g0 += w0 * w0; g1 += w0 * w1; g2 += w0 * w2;
      g3 += w1 * w1; g4 += w1 * w2; g5 += w2 * w2;
    }
    for (int off = 32; off; off >>= 1) {
      g0 += __shfl_down(g0, off, 64); g1 += __shfl_down(g1, off, 64);
      g2 += __shfl_down(g2, off, 64); g3 += __shfl_down(g3, off, 64);
      g4 += __shfl_down(g4, off, 64); g5 += __shfl_down(g5, off, 64);
    }
    if (t == 0) {
      double l00 = sqrt(g0);
      double l10 = g1 / l00, l20 = g2 / l00;
      double l11 = sqrt(g3 - l10 * l10);
      double l21 = (g4 - l10 * l20) / l11;
      double l22 = sqrt(g5 - l20 * l20 - l21 * l21);
      Msh[0] = (float)l00; Msh[1] = (float)l10; Msh[2] = (float)l20;
      Msh[3] = (float)l11; Msh[4] = (float)l21; Msh[5] = (float)l22;
    }
  }
  __syncthreads();
  float m00 = Msh[0], m10 = Msh[1], m20 = Msh[2];
  float m11 = Msh[3], m21 = Msh[4], m22 = Msh[5];

  const float* pb = p + b * PN * 3;
  float4* qws = (float4*)(ws + OFF_H1) + b * PN;  // staged {q, |q|^2}
  // ownership: pair j holds global points i0=(2j)*1024+t and i1=i0+1024
  v2f qx[8], qy[8], qz[8], nq[8], dist[8];
#pragma unroll
  for (int j = 0; j < 8; j++) {
    int i0 = ((2 * j) << 10) + t;
    int i1 = i0 + 1024;
    float x0 = pb[i0 * 3], y0 = pb[i0 * 3 + 1], z0 = pb[i0 * 3 + 2];
    float x1 = pb[i1 * 3], y1 = pb[i1 * 3 + 1], z1 = pb[i1 * 3 + 2];
    qx[j] = (v2f){fmaf(m00, x0, fmaf(m10, y0, m20 * z0)),
                  fmaf(m00, x1, fmaf(m10, y1, m20 * z1))};
    qy[j] = (v2f){fmaf(m11, y0, m21 * z0), fmaf(m11, y1, m21 * z1)};
    qz[j] = (v2f){m22 * z0, m22 * z1};
    nq[j] = __builtin_elementwise_fma(
        qx[j], qx[j],
        __builtin_elementwise_fma(qy[j], qy[j], qz[j] * qz[j]));
    dist[j] = (v2f){1e10f, 1e10f};
    qws[i0] = make_float4(qx[j].x, qy[j].x, qz[j].x, nq[j].x);
    qws[i1] = make_float4(qx[j].y, qy[j].y, qz[j].y, nq[j].y);
  }

  if (t == 0) {
    widx[0] = 0x7fffffff; widx[1] = 0x7fffffff;
    gb[0] = 0u; gb[1] = 0u;
  }
  __syncthreads();                   // q-array + seeds visible to block

  int far = 0;                       // step-0 selection (jnp FPS starts at 0)
  int par = 0;
  for (int k = 0; k < NSAMP; k++) {
    float4 qc = qws[far];            // one uniform b128 load (L2)
    float cx2 = -2.f * qc.x, cy2 = -2.f * qc.y, cz2 = -2.f * qc.z;
    v2f cxv = (v2f){cx2, cx2}, cyv = (v2f){cy2, cy2}, czv = (v2f){cz2, cz2};
    v2f ncv = (v2f){qc.w, qc.w};
#pragma unroll
    for (int j = 0; j < 8; j++) {    // d = n_i - 2<q,c> + n_c, packed
      v2f base = nq[j] + ncv;
      v2f d = __builtin_elementwise_fma(
          qx[j], cxv,
          __builtin_elementwise_fma(qy[j], cyv,
              __builtin_elementwise_fma(qz[j], czv, base)));
      dist[j] = __builtin_elementwise_min(dist[j], d);
    }
    if (t == 0) {                    // off the step-entry critical path
      idx_out[b * NSAMP + k] = far;  // scan emits pre-update far
      widx[par] = 0x7fffffff;        // writers are post-B1 (safe)
      gb[par ^ 1] = 0u;              // readers done pre-B2(k-1); writers post-B2(k)
    }
    // per-thread max of 16 (packed tree)
    v2f t0v = __builtin_elementwise_max(dist[0], dist[1]);
    v2f t1v = __builtin_elementwise_max(dist[2], dist[3]);
    v2f t2v = __builtin_elementwise_max(dist[4], dist[5]);
    v2f t3v = __builtin_elementwise_max(dist[6], dist[7]);
    t0v = __builtin_elementwise_max(t0v, t1v);
    t2v = __builtin_elementwise_max(t2v, t3v);
    t0v = __builtin_elementwise_max(t0v, t2v);
    float tmax = fmaxf(t0v.x, t0v.y);
    // wave max via DPP (row_shr 1/2/4/8, row_bcast 15/31) -> lane 63
    float wv = tmax;
    DPP_MAX(wv, 0x111);
    DPP_MAX(wv, 0x112);
    DPP_MAX(wv, 0x114);
    DPP_MAX(wv, 0x118);
    DPP_MAX(wv, 0x142);
    DPP_MAX(wv, 0x143);
    if ((t & 63) == 63)              // f32>=0 bits are order-monotone
      atomicMax(&gb[par], __float_as_uint(fmaxf(wv, 0.f)));
    __syncthreads();                 // barrier 1: gb[par] final
    float gmax = __uint_as_float(gb[par]);
    if (tmax == gmax) {              // rare claim: index-only scan
      // independent predicated selects, DESCENDING index order:
      // last executed write = smallest matching index (first-index tiebreak)
      int mi = 0x7fffffff;
#pragma unroll
      for (int j = 7; j >= 0; j--) {
        int i0 = ((2 * j) << 10) + t;
        mi = (dist[j].y == gmax) ? i0 + 1024 : mi;
        mi = (dist[j].x == gmax) ? i0 : mi;
      }
      atomicMin(&widx[par], mi);     // smallest global index wins => argmax
    }
    __syncthreads();                 // barrier 2: selection resolved
    far = widx[par];                 // registered for next iteration
    par ^= 1;
  }
}

// ---- K2: GEMM1, split-K over 768 threads ---------------------------------
// h1 = local_feat @ W1_loc + (gf@W1_glob + b1)   [glob part precomputed in K1]
// 8-row tiles x 256 blocks (R8-proven block shape) but 768 threads: half 0
// accumulates c in [0,96), half 1 in [96,192); half 1 deposits partials in
// LDS, half 0 combines + epilogue. Same per-block fixed costs as R8 (the
// R10 regression mechanism), but 12 waves/CU instead of 6 -> halves the
// exposed L2/LDS latency of the serial c-loop.
__global__ __launch_bounds__(768) void k_gemm1(const float* p,
                                               const float* Wc,
                                               const float* bc,
                                               float* ws) {
  __shared__ __align__(16) float ct[HALF * 8];
  __shared__ __align__(16) float part[HID * 8];
  int t = threadIdx.x;
  int row0 = blockIdx.x * 8;
  int b = row0 >> 8;                 // 8 rows never span a batch (256 | 8)
  const int* fidx = (const int*)(ws + OFF_IDX);
  for (int sI = t; sI < 8 * HALF; sI += 768) {  // stage sampled local_feat
    int r = sI / HALF, co = sI % HALF;
    int row = row0 + r;
    int i = fidx[row];
    const float* pp = p + (b * PN + i) * 3;
    float val = bc[co];
    val = fmaf(pp[0], Wc[co], val);
    val = fmaf(pp[1], Wc[HALF + co], val);
    val = fmaf(pp[2], Wc[2 * HALF + co], val);
    ct[co * 8 + r] = val;
  }
  __syncthreads();
  int half = (t >= HID) ? 1 : 0;     // wave-uniform (waves 0-5 vs 6-11)
  int o = t - half * HID;
  const float* w1t = ws + OFF_W1T;
  float acc[8] = {0.f, 0.f, 0.f, 0.f, 0.f, 0.f, 0.f, 0.f};
  int c0 = half * (HALF / 2);
  for (int c = c0; c < c0 + HALF / 2; c++) {
    float w = w1t[c * HID + o];
    float4 a0 = *(const float4*)(ct + c * 8);
    float4 a1 = *(const float4*)(ct + c * 8 + 4);
    acc[0] = fmaf(a0.x, w, acc[0]); acc[1] = fmaf(a0.y, w, acc[1]);
    acc[2] = fmaf(a0.z, w, acc[2]); acc[3] = fmaf(a0.w, w, acc[3]);
    acc[4] = fmaf(a1.x, w, acc[4]); acc[5] = fmaf(a1.y, w, acc[5]);
    acc[6] = fmaf(a1.z, w, acc[6]); acc[7] = fmaf(a1.w, w, acc[7]);
  }
  if (half) {
    *(float4*)(part + o * 8)     = make_float4(acc[0], acc[1], acc[2], acc[3]);
    *(float4*)(part + o * 8 + 4) = make_float4(acc[4], acc[5], acc[6], acc[7]);
  }
  __syncthreads();
  if (!half) {
    float4 p0 = *(const float4*)(part + o * 8);
    float4 p1 = *(const float4*)(part + o * 8 + 4);
    float base = ws[OFF_GFW + b * HID + o];  // includes b1 + glob part
    float sv = 0.f, sq = 0.f;
    float vr[8] = {acc[0] + p0.x, acc[1] + p0.y, acc[2] + p0.z, acc[3] + p0.w,
                   acc[4] + p1.x, acc[5] + p1.y, acc[6] + p1.z, acc[7] + p1.w};
#pragma unroll
    for (int r = 0; r < 8; r++) {
      float v = vr[r] + base;
      ws[OFF_H1 + (row0 + r) * HID + o] = v;
      sv += v; sq = fmaf(v, v, sq);
    }
    atomicAdd(&ws[OFF_SUM1 + o], sv);
    atomicAdd(&ws[OFF_SQ1 + o], sq);
  }
}

// ---- K3: GEMM2, split-K over 768 threads, inline BN1 finalize + ReLU -----
__global__ __launch_bounds__(768) void k_gemm2(const float* b2,
                                               const float* g1,
                                               const float* be1,
                                               float* ws) {
  __shared__ __align__(16) float ht[HID * 8];
  __shared__ __align__(16) float part[HID * 8];
  __shared__ float sc1s[HID], sh1s[HID];
  int t = threadIdx.x;
  int row0 = blockIdx.x * 8;
  if (t < HID) {                      // BN1 finalize, redundantly per block
    float m = ws[OFF_SUM1 + t] * (1.f / ROWS);
    float v = ws[OFF_SQ1 + t] * (1.f / ROWS) - m * m;
    float inv = 1.f / sqrtf(v + BN_EPS);
    float sc = inv * g1[t];
    sc1s[t] = sc;
    sh1s[t] = be1[t] - m * sc;
  }
  __syncthreads();
  for (int sI = t; sI < 8 * HID; sI += 768) {
    int r = sI / HID, c = sI % HID;
    float x = fmaf(ws[OFF_H1 + (row0 + r) * HID + c], sc1s[c], sh1s[c]);
    ht[c * 8 + r] = fmaxf(x, 0.f);
  }
  __syncthreads();
  int half = (t >= HID) ? 1 : 0;     // wave-uniform
  int o = t - half * HID;
  const float* w2t = ws + OFF_W2T;
  float acc[8] = {0.f, 0.f, 0.f, 0.f, 0.f, 0.f, 0.f, 0.f};
  int c0 = half * (HID / 2);
  for (int c = c0; c < c0 + HID / 2; c++) {
    float w = w2t[c * HID + o];
    float4 a0 = *(const float4*)(ht + c * 8);
    float4 a1 = *(const float4*)(ht + c * 8 + 4);
    acc[0] = fmaf(a0.x, w, acc[0]); acc[1] = fmaf(a0.y, w, acc[1]);
    acc[2] = fmaf(a0.z, w, acc[2]); acc[3] = fmaf(a0.w, w, acc[3]);
    acc[4] = fmaf(a1.x, w, acc[4]); acc[5] = fmaf(a1.y, w, acc[5]);
    acc[6] = fmaf(a1.z, w, acc[6]); acc[7] = fmaf(a1.w, w, acc[7]);
  }
  if (half) {
    *(float4*)(part + o * 8)     = make_float4(acc[0], acc[1], acc[2], acc[3]);
    *(float4*)(part + o * 8 + 4) = make_float4(acc[4], acc[5], acc[6], acc[7]);
  }
  __syncthreads();
  if (!half) {
    float4 p0 = *(const float4*)(part + o * 8);
    float4 p1 = *(const float4*)(part + o * 8 + 4);
    float bias = b2[o];
    float sv = 0.f, sq = 0.f;
    float vr[8] = {acc[0] + p0.x, acc[1] + p0.y, acc[2] + p0.z, acc[3] + p0.w,
                   acc[4] + p1.x, acc[5] + p1.y, acc[6] + p1.z, acc[7] + p1.w};
#pragma unroll
    for (int r = 0; r < 8; r++) {
      float v = vr[r] + bias;
      ws[OFF_H2 + (row0 + r) * HID + o] = v;
      sv += v; sq = fmaf(v, v, sq);
    }
    atomicAdd(&ws[OFF_SUM2 + o], sv);
    atomicAdd(&ws[OFF_SQ2 + o], sq);
  }
}

// ---- K4: inline BN2 finalize + affine + ReLU -----------------------------
__global__ __launch_bounds__(256) void k_out(const float* ws, const float* g2,
                                             const float* be2, float* out) {
  int gid = blockIdx.x * 256 + threadIdx.x;
  int i = gid * 4;
  int c = i % HID;                    // multiple of 4
  float4 h  = *(const float4*)(ws + OFF_H2 + i);
  float4 s2 = *(const float4*)(ws + OFF_SUM2 + c);
  float4 q2 = *(const float4*)(ws + OFF_SQ2 + c);
  float4 gv = *(const float4*)(g2 + c);
  float4 bv = *(const float4*)(be2 + c);
  float4 r;
#define BN2(comp) {                                                  \
    float m  = s2.comp * (1.f / ROWS);                               \
    float v  = q2.comp * (1.f / ROWS) - m * m;                       \
    float sc = (1.f / sqrtf(v + BN_EPS)) * gv.comp;                  \
    float sh = bv.comp - m * sc;                                     \
    r.comp = fmaxf(fmaf(h.comp, sc, sh), 0.f); }
  BN2(x) BN2(y) BN2(z) BN2(w)
#undef BN2
  ((float4*)out)[gid] = r;
}

extern "C" void kernel_launch(void* const* d_in, const int* in_sizes, int n_in,
                              void* d_out, int out_size, void* d_ws, size_t ws_size,
                              hipStream_t stream) {
  const float* p   = (const float*)d_in[0];
  // d_in[1] = N (int scalar, always 256)
  const float* pf  = (const float*)d_in[2];
  const float* Wf  = (const float*)d_in[3];
  const float* bfe = (const float*)d_in[4];
  const float* Wc  = (const float*)d_in[5];
  const float* bc  = (const float*)d_in[6];
  const float* W1  = (const float*)d_in[7];
  const float* b1  = (const float*)d_in[8];
  const float* g1  = (const float*)d_in[9];
  const float* be1 = (const float*)d_in[10];
  const float* W2  = (const float*)d_in[11];
  const float* b2  = (const float*)d_in[12];
  const float* g2  = (const float*)d_in[13];
  const float* be2 = (const float*)d_in[14];
  float* ws = (float*)d_ws;

  hipLaunchKernelGGL(k_main,  dim3(33),  dim3(1024), 0, stream,
                     p, Wc, pf, Wf, bfe, W1, b1, W2, ws);
  hipLaunchKernelGGL(k_gemm1, dim3(256), dim3(768), 0, stream, p, Wc, bc, ws);
  hipLaunchKernelGGL(k_gemm2, dim3(256), dim3(768), 0, stream, b2, g1, be1, ws);
  hipLaunchKernelGGL(k_out,   dim3(768), dim3(256), 0, stream,
                     ws, g2, be2, (float*)d_out);
}